// Round 2
// baseline (3012.962 us; speedup 1.0000x reference)
//
#include <hip/hip_runtime.h>
#include <math.h>

#define B_ 16
#define D_ 256
#define T_ 1024
#define K_ 8192
#define N_ (B_*T_)          // 16384 rows

// ---------------- ws layout (4-byte words) ----------------
// [0      .. 32767]  packed   (u64[16384]: monotone-encoded dist<<32 | idx)
// [32768  .. 40959]  hist     (int, 8192)
// [40960]            lossAcc  (float)
// [40968  .. 49159]  e2       (float, 8192)
// [49160  .. 65543]  idx      (int, 16384)
// total 65544 words = 262 KB

// init: packed = 0xFFFFFFFF.., hist = 0, lossAcc = 0
__global__ void vq_init(int* __restrict__ p, int n) {
    int i = blockIdx.x * 256 + threadIdx.x;
    if (i < n) p[i] = (i < 32768) ? -1 : 0;
}

// ||emb_k||^2 : one wave per code, 4 codes per block
__global__ void vq_e2(const float* __restrict__ emb, float* __restrict__ e2) {
    const int tid  = threadIdx.x;
    const int lane = tid & 63;
    const int k    = blockIdx.x * 4 + (tid >> 6);
    float4 v = *(const float4*)&emb[k * D_ + lane * 4];
    float s = v.x*v.x + v.y*v.y + v.z*v.z + v.w*v.w;
    #pragma unroll
    for (int off = 32; off >= 1; off >>= 1) s += __shfl_down(s, off, 64);
    if (lane == 0) e2[k] = s;
}

// fused distance-GEMM + argmin.  grid = 1024 blocks:
//   blockIdx>>3 = row-tile (128 rows), blockIdx&7 = K-split (1024 codes each)
// block tile 128 rows x 128 codes, 16x16 threads, 8x8 micro-tile, d-chunk 32.
// LDS 36.9KB -> 4 blocks/CU -> 4 waves/SIMD.
__global__ __launch_bounds__(256, 4)
void vq_argmin(const float* __restrict__ z_e, const float* __restrict__ emb,
               const float* __restrict__ e2,
               unsigned long long* __restrict__ packed)
{
    __shared__ float xs[128 * 36];   // [row][d] stride 36 (pad 4, 16B-aligned rows)
    __shared__ float es[128 * 36];   // [code][d]

    const int tid = threadIdx.x;
    const int tx  = tid & 15;        // code group
    const int ty  = tid >> 4;        // row group
    const int rb  = blockIdx.x >> 3;
    const int ks  = blockIdx.x & 7;
    const int n0  = rb * 128;        // 128 | T_, so one b per tile
    const int b   = n0 >> 10;
    const int t0  = n0 & 1023;
    const int kbase = ks * 1024;

    float bst[8]; int bidx[8];
    #pragma unroll
    for (int i = 0; i < 8; i++) { bst[i] = 3.4e38f; bidx[i] = 0; }

    for (int kc = 0; kc < 8; ++kc) {
        const int k0 = kbase + kc * 128;
        float acc[8][8];
        #pragma unroll
        for (int i = 0; i < 8; i++)
            #pragma unroll
            for (int j = 0; j < 8; j++) acc[i][j] = 0.f;

        for (int dc = 0; dc < 8; ++dc) {
            const int d0 = dc * 32;
            __syncthreads();                       // protect LDS reuse
            // stage x: 128 rows x 32 d.  per wave: 16 t x 4 d
            //   -> global: 4x 64B segments; LDS write banks (4*tlow+dlow)%32: 2-way (free)
            #pragma unroll
            for (int p = 0; p < 16; p++) {
                int f  = p * 256 + tid;
                int tt = ((f >> 6) & 7) * 16 + (f & 15);
                int dd = ((f >> 9) & 7) * 4 + ((f >> 4) & 3);
                xs[tt * 36 + dd] = z_e[(b * D_ + d0 + dd) * T_ + t0 + tt];
            }
            // stage e: 128 codes x 32 d, float4 (128B contiguous per code row)
            #pragma unroll
            for (int p = 0; p < 4; p++) {
                int g = p * 256 + tid;
                int c = g >> 3;                    // 0..127
                int q = (g & 7) << 2;              // 0..28
                *(float4*)&es[c * 36 + q] =
                    *(const float4*)&emb[(k0 + c) * D_ + d0 + q];
            }
            __syncthreads();
            #pragma unroll 4
            for (int d = 0; d < 32; d += 4) {
                float4 ev[8];
                #pragma unroll
                for (int j = 0; j < 8; j++)
                    ev[j] = *(const float4*)&es[(tx + 16 * j) * 36 + d];
                #pragma unroll
                for (int i = 0; i < 8; i++) {
                    float4 xv = *(const float4*)&xs[(ty + 16 * i) * 36 + d];
                    #pragma unroll
                    for (int j = 0; j < 8; j++) {
                        // pure FMA chain: exactly 4 v_fma_f32 per 4 MACs
                        acc[i][j] = __builtin_fmaf(xv.x, ev[j].x, acc[i][j]);
                        acc[i][j] = __builtin_fmaf(xv.y, ev[j].y, acc[i][j]);
                        acc[i][j] = __builtin_fmaf(xv.z, ev[j].z, acc[i][j]);
                        acc[i][j] = __builtin_fmaf(xv.w, ev[j].w, acc[i][j]);
                    }
                }
            }
        }
        // distances + running argmin (strict < keeps first-min; c ascending in j,kc)
        #pragma unroll
        for (int j = 0; j < 8; j++) {
            const int c = k0 + tx + 16 * j;
            const float ev2 = e2[c];
            #pragma unroll
            for (int i = 0; i < 8; i++) {
                float dist = __builtin_fmaf(acc[i][j], -2.f, ev2);
                if (dist < bst[i]) { bst[i] = dist; bidx[i] = c; }
            }
        }
    }
    __syncthreads();
    // cross-tx reduction per row via LDS (reuse xs/es)
    float* rmin = xs;                 // [128][16]
    int*   ridx = (int*)es;
    #pragma unroll
    for (int i = 0; i < 8; i++) {
        rmin[(ty + 16 * i) * 16 + tx] = bst[i];
        ridx[(ty + 16 * i) * 16 + tx] = bidx[i];
    }
    __syncthreads();
    if (tid < 128) {
        const int r = tid;
        float bd = rmin[r * 16]; int bi = ridx[r * 16];
        #pragma unroll
        for (int x = 1; x < 16; x++) {
            float d2 = rmin[r * 16 + x]; int i2 = ridx[r * 16 + x];
            if (d2 < bd || (d2 == bd && i2 < bi)) { bd = d2; bi = i2; }
        }
        // monotone float encode; low 32 bits = idx  =>  atomicMin gives
        // (min dist, then min idx) — exactly argmin-first semantics.
        unsigned ub = __float_as_uint(bd);
        unsigned mu = (ub & 0x80000000u) ? ~ub : (ub | 0x80000000u);
        unsigned long long pk = ((unsigned long long)mu << 32) | (unsigned)bi;
        atomicMin(&packed[n0 + r], pk);
    }
}

// unpack per-row winner; build histogram
__global__ void vq_reduce(const unsigned long long* __restrict__ packed,
                          int* __restrict__ idx, int* __restrict__ hist)
{
    int r = blockIdx.x * 256 + threadIdx.x;
    if (r >= N_) return;
    int bi = (int)(packed[r] & 0xFFFFFFFFull);
    idx[r] = bi;
    atomicAdd(&hist[bi], 1);
}

// gather z_q, write transposed output, accumulate commitment loss
__global__ __launch_bounds__(256)
void vq_gather(const float* __restrict__ z_e, const float* __restrict__ emb,
               const int* __restrict__ idx, float* __restrict__ out,
               float* __restrict__ lossAcc)
{
    __shared__ float es[64 * 259];   // [t][d], stride 259 -> conflict-free col reads
    __shared__ int   codes[64];
    __shared__ float red[4];
    const int tid = threadIdx.x;
    const int bb  = blockIdx.x >> 4;
    const int t0  = (blockIdx.x & 15) << 6;
    if (tid < 64) codes[tid] = idx[bb * T_ + t0 + tid];
    __syncthreads();
    for (int p = 0; p < 64; p++) {
        es[p * 259 + tid] = emb[codes[p] * D_ + tid];
    }
    __syncthreads();
    const int t  = tid & 63;
    const int ds = tid >> 6;
    float ls = 0.f;
    #pragma unroll 4
    for (int jj = 0; jj < 64; jj++) {
        int d = ds * 64 + jj;
        float e = es[t * 259 + d];
        int gi = (bb * D_ + d) * T_ + t0 + t;
        float x = z_e[gi];
        out[gi] = e;                      // coalesced 256B stores per wave
        float df = e - x;
        ls += df * df;
    }
    #pragma unroll
    for (int off = 32; off >= 1; off >>= 1) ls += __shfl_down(ls, off, 64);
    if ((tid & 63) == 0) red[tid >> 6] = ls;
    __syncthreads();
    if (tid == 0) atomicAdd(lossAcc, red[0] + red[1] + red[2] + red[3]);
}

// entropy -> perplexity, scale loss
__global__ void vq_finalize(const int* __restrict__ hist, const float* __restrict__ lossAcc,
                            float* __restrict__ out_scalars)
{
    __shared__ float red[256];
    const int tid = threadIdx.x;
    float s = 0.f;
    for (int k = tid; k < K_; k += 256) {
        float p = (float)hist[k] * (1.0f / (float)N_);
        s += p * logf(p + 1e-10f);
    }
    red[tid] = s;
    __syncthreads();
    for (int off = 128; off >= 1; off >>= 1) {
        if (tid < off) red[tid] += red[tid + off];
        __syncthreads();
    }
    if (tid == 0) {
        out_scalars[0] = 0.25f * lossAcc[0] * (1.f / (float)(N_ * D_));  // ALPHA*BETA*mean
        out_scalars[1] = expf(-red[0]);
    }
}

extern "C" void kernel_launch(void* const* d_in, const int* in_sizes, int n_in,
                              void* d_out, int out_size, void* d_ws, size_t ws_size,
                              hipStream_t stream) {
    const float* z_e = (const float*)d_in[0];
    const float* emb = (const float*)d_in[1];
    float* out = (float*)d_out;

    int*                ws      = (int*)d_ws;
    unsigned long long* packed  = (unsigned long long*)d_ws;
    int*                hist    = ws + 32768;
    float*              lossAcc = (float*)(ws + 40960);
    float*              e2      = (float*)(ws + 40968);
    int*                idx     = ws + 49160;

    vq_init    <<<161,  256, 0, stream>>>(ws, 40968);           // packed + hist + lossAcc
    vq_e2      <<<2048, 256, 0, stream>>>(emb, e2);
    vq_argmin  <<<1024, 256, 0, stream>>>(z_e, emb, e2, packed);
    vq_reduce  <<<64,   256, 0, stream>>>(packed, idx, hist);
    vq_gather  <<<256,  256, 0, stream>>>(z_e, emb, idx, out, lossAcc);
    vq_finalize<<<1,    256, 0, stream>>>(hist, lossAcc, out + 4194304);
}

// Round 4
// 1021.288 us; speedup vs baseline: 2.9502x; 2.9502x over previous
//
#include <hip/hip_runtime.h>
#include <math.h>

#define B_ 16
#define D_ 256
#define T_ 1024
#define K_ 8192
#define N_ (B_*T_)          // 16384 rows

// ---------------- ws layout (4-byte words) ----------------
// [0      .. 32767]  packed   (u64[16384]: monotone-encoded dist<<32 | idx)
// [32768  .. 40959]  hist     (int, 8192)
// [40960]            lossAcc  (float)
// [40968  .. 49159]  e2       (float, 8192)
// [49160  .. 65543]  idx      (int, 16384)
// total 65544 words = 262 KB

// init: packed = 0xFFFFFFFF.., hist = 0, lossAcc = 0
__global__ void vq_init(int* __restrict__ p, int n) {
    int i = blockIdx.x * 256 + threadIdx.x;
    if (i < n) p[i] = (i < 32768) ? -1 : 0;
}

// ||emb_k||^2 : one wave per code, 4 codes per block
__global__ void vq_e2(const float* __restrict__ emb, float* __restrict__ e2) {
    const int tid  = threadIdx.x;
    const int lane = tid & 63;
    const int k    = blockIdx.x * 4 + (tid >> 6);
    float4 v = *(const float4*)&emb[k * D_ + lane * 4];
    float s = v.x*v.x + v.y*v.y + v.z*v.z + v.w*v.w;
    #pragma unroll
    for (int off = 32; off >= 1; off >>= 1) s += __shfl_down(s, off, 64);
    if (lane == 0) e2[k] = s;
}

// fused distance-GEMM + argmin.  grid = 1024 blocks:
//   blockIdx>>3 = row-tile (128 rows), blockIdx&7 = K-split (1024 codes each)
// block tile 128 rows x 128 codes, 16x16 threads, 8x8 micro-tile, d-chunk 32.
// LDS 36.9KB + 128 VGPR -> 4 blocks/CU.
// NOTE: __launch_bounds__ min-waves MUST stay 2: asking for 4 makes the
// allocator target 8 waves/EU (64 VGPR) and spill acc[8][8] to scratch
// (round-2 post-mortem: FETCH 0.6->3.6GB, WRITE 49MB->8.7GB, 2.5x slower).
__global__ __launch_bounds__(256, 2)
void vq_argmin(const float* __restrict__ z_e, const float* __restrict__ emb,
               const float* __restrict__ e2,
               unsigned long long* __restrict__ packed)
{
    __shared__ float xs[128 * 36];   // [row][d] stride 36 (pad 4, 16B-aligned rows)
    __shared__ float es[128 * 36];   // [code][d]

    const int tid = threadIdx.x;
    const int tx  = tid & 15;        // code group
    const int ty  = tid >> 4;        // row group
    const int rb  = blockIdx.x >> 3;
    const int ks  = blockIdx.x & 7;
    const int n0  = rb * 128;        // 128 | T_, so one b per tile
    const int b   = n0 >> 10;
    const int t0  = n0 & 1023;
    const int kbase = ks * 1024;

    float bst[8]; int bidx[8];
    #pragma unroll
    for (int i = 0; i < 8; i++) { bst[i] = 3.4e38f; bidx[i] = 0; }

    for (int kc = 0; kc < 8; ++kc) {
        const int k0 = kbase + kc * 128;
        float acc[8][8];
        #pragma unroll
        for (int i = 0; i < 8; i++)
            #pragma unroll
            for (int j = 0; j < 8; j++) acc[i][j] = 0.f;

        for (int dc = 0; dc < 8; ++dc) {
            const int d0 = dc * 32;
            __syncthreads();                       // protect LDS reuse
            // stage x: 128 rows x 32 d.  per wave: 16 t x 4 d
            //   -> global: 4x 64B segments; LDS write banks (4*tlow+dlow)%32: 2-way (free)
            #pragma unroll
            for (int p = 0; p < 16; p++) {
                int f  = p * 256 + tid;
                int tt = ((f >> 6) & 7) * 16 + (f & 15);
                int dd = ((f >> 9) & 7) * 4 + ((f >> 4) & 3);
                xs[tt * 36 + dd] = z_e[(b * D_ + d0 + dd) * T_ + t0 + tt];
            }
            // stage e: 128 codes x 32 d, float4 (128B contiguous per code row)
            #pragma unroll
            for (int p = 0; p < 4; p++) {
                int g = p * 256 + tid;
                int c = g >> 3;                    // 0..127
                int q = (g & 7) << 2;              // 0..28
                *(float4*)&es[c * 36 + q] =
                    *(const float4*)&emb[(k0 + c) * D_ + d0 + q];
            }
            __syncthreads();
            #pragma unroll 4
            for (int d = 0; d < 32; d += 4) {
                float4 ev[8];
                #pragma unroll
                for (int j = 0; j < 8; j++)
                    ev[j] = *(const float4*)&es[(tx + 16 * j) * 36 + d];
                #pragma unroll
                for (int i = 0; i < 8; i++) {
                    float4 xv = *(const float4*)&xs[(ty + 16 * i) * 36 + d];
                    #pragma unroll
                    for (int j = 0; j < 8; j++) {
                        // pure FMA chain: exactly 4 v_fma_f32 per 4 MACs
                        acc[i][j] = __builtin_fmaf(xv.x, ev[j].x, acc[i][j]);
                        acc[i][j] = __builtin_fmaf(xv.y, ev[j].y, acc[i][j]);
                        acc[i][j] = __builtin_fmaf(xv.z, ev[j].z, acc[i][j]);
                        acc[i][j] = __builtin_fmaf(xv.w, ev[j].w, acc[i][j]);
                    }
                }
            }
        }
        // distances + running argmin (strict < keeps first-min; c ascending in j,kc)
        #pragma unroll
        for (int j = 0; j < 8; j++) {
            const int c = k0 + tx + 16 * j;
            const float ev2 = e2[c];
            #pragma unroll
            for (int i = 0; i < 8; i++) {
                float dist = __builtin_fmaf(acc[i][j], -2.f, ev2);
                if (dist < bst[i]) { bst[i] = dist; bidx[i] = c; }
            }
        }
    }
    __syncthreads();
    // cross-tx reduction per row via LDS (reuse xs/es)
    float* rmin = xs;                 // [128][16]
    int*   ridx = (int*)es;
    #pragma unroll
    for (int i = 0; i < 8; i++) {
        rmin[(ty + 16 * i) * 16 + tx] = bst[i];
        ridx[(ty + 16 * i) * 16 + tx] = bidx[i];
    }
    __syncthreads();
    if (tid < 128) {
        const int r = tid;
        float bd = rmin[r * 16]; int bi = ridx[r * 16];
        #pragma unroll
        for (int x = 1; x < 16; x++) {
            float d2 = rmin[r * 16 + x]; int i2 = ridx[r * 16 + x];
            if (d2 < bd || (d2 == bd && i2 < bi)) { bd = d2; bi = i2; }
        }
        // monotone float encode; low 32 bits = idx  =>  atomicMin gives
        // (min dist, then min idx) — exactly argmin-first semantics.
        unsigned ub = __float_as_uint(bd);
        unsigned mu = (ub & 0x80000000u) ? ~ub : (ub | 0x80000000u);
        unsigned long long pk = ((unsigned long long)mu << 32) | (unsigned)bi;
        atomicMin(&packed[n0 + r], pk);
    }
}

// unpack per-row winner; build histogram
__global__ void vq_reduce(const unsigned long long* __restrict__ packed,
                          int* __restrict__ idx, int* __restrict__ hist)
{
    int r = blockIdx.x * 256 + threadIdx.x;
    if (r >= N_) return;
    int bi = (int)(packed[r] & 0xFFFFFFFFull);
    idx[r] = bi;
    atomicAdd(&hist[bi], 1);
}

// gather z_q, write transposed output, accumulate commitment loss
__global__ __launch_bounds__(256)
void vq_gather(const float* __restrict__ z_e, const float* __restrict__ emb,
               const int* __restrict__ idx, float* __restrict__ out,
               float* __restrict__ lossAcc)
{
    __shared__ float es[64 * 259];   // [t][d], stride 259 -> conflict-free col reads
    __shared__ int   codes[64];
    __shared__ float red[4];
    const int tid = threadIdx.x;
    const int bb  = blockIdx.x >> 4;
    const int t0  = (blockIdx.x & 15) << 6;
    if (tid < 64) codes[tid] = idx[bb * T_ + t0 + tid];
    __syncthreads();
    for (int p = 0; p < 64; p++) {
        es[p * 259 + tid] = emb[codes[p] * D_ + tid];
    }
    __syncthreads();
    const int t  = tid & 63;
    const int ds = tid >> 6;
    float ls = 0.f;
    #pragma unroll 4
    for (int jj = 0; jj < 64; jj++) {
        int d = ds * 64 + jj;
        float e = es[t * 259 + d];
        int gi = (bb * D_ + d) * T_ + t0 + t;
        float x = z_e[gi];
        out[gi] = e;                      // coalesced 256B stores per wave
        float df = e - x;
        ls += df * df;
    }
    #pragma unroll
    for (int off = 32; off >= 1; off >>= 1) ls += __shfl_down(ls, off, 64);
    if ((tid & 63) == 0) red[tid >> 6] = ls;
    __syncthreads();
    if (tid == 0) atomicAdd(lossAcc, red[0] + red[1] + red[2] + red[3]);
}

// entropy -> perplexity, scale loss
__global__ void vq_finalize(const int* __restrict__ hist, const float* __restrict__ lossAcc,
                            float* __restrict__ out_scalars)
{
    __shared__ float red[256];
    const int tid = threadIdx.x;
    float s = 0.f;
    for (int k = tid; k < K_; k += 256) {
        float p = (float)hist[k] * (1.0f / (float)N_);
        s += p * logf(p + 1e-10f);
    }
    red[tid] = s;
    __syncthreads();
    for (int off = 128; off >= 1; off >>= 1) {
        if (tid < off) red[tid] += red[tid + off];
        __syncthreads();
    }
    if (tid == 0) {
        out_scalars[0] = 0.25f * lossAcc[0] * (1.f / (float)(N_ * D_));  // ALPHA*BETA*mean
        out_scalars[1] = expf(-red[0]);
    }
}

extern "C" void kernel_launch(void* const* d_in, const int* in_sizes, int n_in,
                              void* d_out, int out_size, void* d_ws, size_t ws_size,
                              hipStream_t stream) {
    const float* z_e = (const float*)d_in[0];
    const float* emb = (const float*)d_in[1];
    float* out = (float*)d_out;

    int*                ws      = (int*)d_ws;
    unsigned long long* packed  = (unsigned long long*)d_ws;
    int*                hist    = ws + 32768;
    float*              lossAcc = (float*)(ws + 40960);
    float*              e2      = (float*)(ws + 40968);
    int*                idx     = ws + 49160;

    vq_init    <<<161,  256, 0, stream>>>(ws, 40968);           // packed + hist + lossAcc
    vq_e2      <<<2048, 256, 0, stream>>>(emb, e2);
    vq_argmin  <<<1024, 256, 0, stream>>>(z_e, emb, e2, packed);
    vq_reduce  <<<64,   256, 0, stream>>>(packed, idx, hist);
    vq_gather  <<<256,  256, 0, stream>>>(z_e, emb, idx, out, lossAcc);
    vq_finalize<<<1,    256, 0, stream>>>(hist, lossAcc, out + 4194304);
}

// Round 6
// 580.203 us; speedup vs baseline: 5.1929x; 1.7602x over previous
//
#include <hip/hip_runtime.h>
#include <math.h>

#define B_ 16
#define D_ 256
#define T_ 1024
#define K_ 8192
#define N_ (B_*T_)          // 16384 rows

typedef _Float16 f16;
typedef _Float16 f16x4 __attribute__((ext_vector_type(4)));
typedef _Float16 f16x8 __attribute__((ext_vector_type(8)));
typedef float    f32x16 __attribute__((ext_vector_type(16)));

#define INV4096F (1.0f/4096.0f)

// ---- ws byte offsets (total ~393 KB — well inside the proven-safe range) ----
#define WS_E2    0u        // f32 [8192]      exact ||e||^2
#define WS_CAND  32768u    // int [16384][4]  top-2 per K-half
#define WS_IDX   294912u   // int [16384]
#define WS_HIST  360448u   // int [8192]
#define WS_LOSS  393216u   // f32 [1] (contiguous with hist for zeroing)

__global__ void vq_init(int* __restrict__ p, int n) {
    int i = blockIdx.x * 256 + threadIdx.x;
    if (i < n) p[i] = 0;
}

// exact ||emb_k||^2 from fp32
__global__ void vq_e2(const float* __restrict__ emb, float* __restrict__ e2) {
    const int tid  = threadIdx.x;
    const int lane = tid & 63;
    const int k    = blockIdx.x * 4 + (tid >> 6);
    float4 v = *(const float4*)&emb[k * D_ + lane * 4];
    float s = v.x*v.x + v.y*v.y + v.z*v.z + v.w*v.w;
    #pragma unroll
    for (int off = 32; off >= 1; off >>= 1) s += __shfl_down(s, off, 64);
    if (lane == 0) e2[k] = s;
}

// MFMA distance pass. grid = 256: (row-tile of 128) x (K-half of 4096 codes).
// In-kernel fp32->f16 hi/lo split (no prep kernels, no big ws buffers):
//   A: full-D x frags in regs (128 VGPR), loaded+converted from z_e once.
//   B: per-chunk emb staged fp32->f16 into XOR-swizzled LDS [32][256] halfs,
//      byte ^= (row&31)<<4  ->  16B-unit%32 = k_unit ^ row: zero bank conflict
//      on both f16x4 writes and ds_read_b128 reads (T2 pattern).
// dist = e2 - 2*(acc_hh + (acc_hl + acc_lh)/4096); exact-fp32 refine fixes tails.
__global__ __launch_bounds__(256, 1)
void vq_mfma(const float* __restrict__ z_e, const float* __restrict__ emb,
             const float* __restrict__ e2g, int* __restrict__ cand)
{
    __shared__ char smem[32768];
    char*  BH = smem;                    // [32][512B] halfs, swizzled
    char*  BL = smem + 16384;
    float* rd = (float*)smem;            // epilogue alias [128][32]
    int*   ri = (int*)(smem + 16384);

    const int tid = threadIdx.x;
    const int w   = tid >> 6;
    const int l   = tid & 63;
    const int lr  = l & 31;              // A row / B col within tile
    const int lg  = l >> 5;              // K-group (8 halfs each)
    const int rb  = blockIdx.x >> 1;
    const int ks  = blockIdx.x & 1;
    const int n0  = rb * 128;            // 128 | 1024 -> single b per tile
    const int b   = n0 >> 10;
    const int t0  = n0 & 1023;

    // ---- A fragments: load 128 x-values from z_e, split in regs ----
    // addr: z_e[(b*D + d)*T + t], t = t0 + w*32 + lr  (lane-coalesced 128B)
    f16x8 ah[16], al[16];
    {
        const float* xp = z_e + ((size_t)b * D_ + lg * 8) * T_ + t0 + w * 32 + lr;
        #pragma unroll
        for (int k8 = 0; k8 < 16; k8++) {
            #pragma unroll
            for (int u = 0; u < 8; u++) {
                float v = xp[(k8 * 16 + u) * T_];
                f16 h = (f16)v;
                ah[k8][u] = h;
                al[k8][u] = (f16)((v - (float)h) * 4096.0f);
            }
        }
    }

    float bst[16]; int bidx[16];
    #pragma unroll
    for (int i = 0; i < 16; i++) { bst[i] = 3.4e38f; bidx[i] = 0; }

    for (int ch = 0; ch < 128; ++ch) {
        const int k0 = ks * 4096 + ch * 32;
        __syncthreads();                  // previous chunk's LDS reads done
        // stage 32 codes x 256 d: fp32 -> hi/lo halfs, swizzled
        #pragma unroll
        for (int p = 0; p < 8; p++) {
            int u   = p * 256 + tid;      // float4 unit 0..2047
            int row = u >> 6;             // 0..31
            int q   = (u & 63) << 2;      // d offset 0..252
            float4 v = *(const float4*)&emb[(k0 + row) * D_ + q];
            f16x4 h, lo;
            h[0] = (f16)v.x; lo[0] = (f16)((v.x - (float)h[0]) * 4096.0f);
            h[1] = (f16)v.y; lo[1] = (f16)((v.y - (float)h[1]) * 4096.0f);
            h[2] = (f16)v.z; lo[2] = (f16)((v.z - (float)h[2]) * 4096.0f);
            h[3] = (f16)v.w; lo[3] = (f16)((v.w - (float)h[3]) * 4096.0f);
            int byteoff = row * 512 + (((q << 1)) ^ ((row & 31) << 4));
            *(f16x4*)(BH + byteoff) = h;
            *(f16x4*)(BL + byteoff) = lo;
        }
        float e2v = e2g[k0 + lr];
        __syncthreads();

        f32x16 acch, accl;
        #pragma unroll
        for (int i = 0; i < 16; i++) { acch[i] = 0.f; accl[i] = 0.f; }
        const int sb = lr * 512;
        #pragma unroll
        for (int k8 = 0; k8 < 16; k8++) {
            int off = (k8 * 32 + lg * 16) ^ ((lr & 31) << 4);
            f16x8 bh = *(const f16x8*)(BH + sb + off);
            f16x8 bl = *(const f16x8*)(BL + sb + off);
            acch = __builtin_amdgcn_mfma_f32_32x32x16_f16(ah[k8], bh, acch, 0, 0, 0);
            accl = __builtin_amdgcn_mfma_f32_32x32x16_f16(ah[k8], bl, accl, 0, 0, 0);
            accl = __builtin_amdgcn_mfma_f32_32x32x16_f16(al[k8], bh, accl, 0, 0, 0);
        }
        const int cc = k0 + lr;           // chunk ascending -> strict < keeps first-min
        #pragma unroll
        for (int i = 0; i < 16; i++) {
            float s    = fmaf(accl[i], INV4096F, acch[i]);
            float dist = fmaf(s, -2.0f, e2v);
            if (dist < bst[i]) { bst[i] = dist; bidx[i] = cc; }
        }
    }

    __syncthreads();
    // C/D layout (m74/m101): col=lane&31, row=(reg&3)+8*(reg>>2)+4*(lane>>5)
    #pragma unroll
    for (int i = 0; i < 16; i++) {
        int r = 4 * lg + (i & 3) + 8 * (i >> 2);
        rd[(w * 32 + r) * 32 + lr] = bst[i];
        ri[(w * 32 + r) * 32 + lr] = bidx[i];
    }
    __syncthreads();
    if (tid < 128) {
        float d1 = 3.4e38f, d2 = 3.4e38f; int i1 = 0x7fffffff, i2 = 0x7fffffff;
        for (int x = 0; x < 32; x++) {
            float dv = rd[tid * 32 + x]; int iv = ri[tid * 32 + x];
            if (dv < d1 || (dv == d1 && iv < i1)) { d2 = d1; i2 = i1; d1 = dv; i1 = iv; }
            else if (dv < d2 || (dv == d2 && iv < i2)) { d2 = dv; i2 = iv; }
        }
        int n = n0 + tid;
        cand[n * 4 + ks * 2]     = i1;
        cand[n * 4 + ks * 2 + 1] = i2;
    }
}

// exact fp32 re-rank of the 4 candidates per row -> final idx + hist
__global__ __launch_bounds__(256)
void vq_refine(const float* __restrict__ z_e, const float* __restrict__ emb,
               const float* __restrict__ e2g, const int* __restrict__ cand,
               int* __restrict__ idx, int* __restrict__ hist)
{
    int g   = blockIdx.x * 256 + threadIdx.x;   // N_*4 threads
    int row = g >> 2;
    int j   = g & 3;
    int c   = cand[row * 4 + j];
    int b   = row >> 10;
    int t   = row & 1023;
    const float* xp = z_e + (size_t)b * D_ * T_ + t;
    const float* ep = emb + (size_t)c * D_;
    float s = 0.f;
    #pragma unroll 8
    for (int d = 0; d < D_; d++)
        s = fmaf(xp[(size_t)d * T_], ep[d], s);
    float dist = fmaf(s, -2.0f, e2g[c]);
    // reduce over the 4 candidate lanes (lanes j=0..3 are adjacent)
    #pragma unroll
    for (int off = 1; off <= 2; off <<= 1) {
        float od = __shfl_xor(dist, off, 64);
        int   oc = __shfl_xor(c,    off, 64);
        if (od < dist || (od == dist && oc < c)) { dist = od; c = oc; }
    }
    if (j == 0) {
        idx[row] = c;
        atomicAdd(&hist[c], 1);
    }
}

// gather z_q (exact fp32 emb), transposed out, commitment loss
__global__ __launch_bounds__(256)
void vq_gather(const float* __restrict__ z_e, const float* __restrict__ emb,
               const int* __restrict__ idx, float* __restrict__ out,
               float* __restrict__ lossAcc)
{
    __shared__ float es[64 * 259];
    __shared__ int   codes[64];
    __shared__ float red[4];
    const int tid = threadIdx.x;
    const int bb  = blockIdx.x >> 4;
    const int t0  = (blockIdx.x & 15) << 6;
    if (tid < 64) codes[tid] = idx[bb * T_ + t0 + tid];
    __syncthreads();
    for (int p = 0; p < 64; p++) {
        es[p * 259 + tid] = emb[codes[p] * D_ + tid];
    }
    __syncthreads();
    const int t  = tid & 63;
    const int ds = tid >> 6;
    float ls = 0.f;
    #pragma unroll 4
    for (int jj = 0; jj < 64; jj++) {
        int d = ds * 64 + jj;
        float e = es[t * 259 + d];
        int gi = (bb * D_ + d) * T_ + t0 + t;
        float x = z_e[gi];
        out[gi] = e;
        float df = e - x;
        ls += df * df;
    }
    #pragma unroll
    for (int off = 32; off >= 1; off >>= 1) ls += __shfl_down(ls, off, 64);
    if ((tid & 63) == 0) red[tid >> 6] = ls;
    __syncthreads();
    if (tid == 0) atomicAdd(lossAcc, red[0] + red[1] + red[2] + red[3]);
}

__global__ void vq_finalize(const int* __restrict__ hist, const float* __restrict__ lossAcc,
                            float* __restrict__ out_scalars)
{
    __shared__ float red[256];
    const int tid = threadIdx.x;
    float s = 0.f;
    for (int k = tid; k < K_; k += 256) {
        float p = (float)hist[k] * (1.0f / (float)N_);
        s += p * logf(p + 1e-10f);
    }
    red[tid] = s;
    __syncthreads();
    for (int off = 128; off >= 1; off >>= 1) {
        if (tid < off) red[tid] += red[tid + off];
        __syncthreads();
    }
    if (tid == 0) {
        out_scalars[0] = 0.25f * lossAcc[0] * (1.f / (float)(N_ * D_));
        out_scalars[1] = expf(-red[0]);
    }
}

extern "C" void kernel_launch(void* const* d_in, const int* in_sizes, int n_in,
                              void* d_out, int out_size, void* d_ws, size_t ws_size,
                              hipStream_t stream) {
    const float* z_e = (const float*)d_in[0];
    const float* emb = (const float*)d_in[1];
    float* out = (float*)d_out;
    char*  ws  = (char*)d_ws;

    float* e2      = (float*)(ws + WS_E2);
    int*   cand    = (int*)(ws + WS_CAND);
    int*   idx     = (int*)(ws + WS_IDX);
    int*   hist    = (int*)(ws + WS_HIST);
    float* lossAcc = (float*)(ws + WS_LOSS);

    vq_init    <<<33,   256, 0, stream>>>(hist, 8193);           // hist + lossAcc
    vq_e2      <<<2048, 256, 0, stream>>>(emb, e2);
    vq_mfma    <<<256,  256, 0, stream>>>(z_e, emb, e2, cand);
    vq_refine  <<<256,  256, 0, stream>>>(z_e, emb, e2, cand, idx, hist);
    vq_gather  <<<256,  256, 0, stream>>>(z_e, emb, idx, out, lossAcc);
    vq_finalize<<<1,    256, 0, stream>>>(hist, lossAcc, out + 4194304);
}

// Round 7
// 416.992 us; speedup vs baseline: 7.2255x; 1.3914x over previous
//
#include <hip/hip_runtime.h>
#include <math.h>

#define B_ 16
#define D_ 256
#define T_ 1024
#define K_ 8192
#define N_ (B_*T_)          // 16384 rows

typedef _Float16 f16;
typedef _Float16 f16x4 __attribute__((ext_vector_type(4)));
typedef _Float16 f16x8 __attribute__((ext_vector_type(8)));
typedef float    f32x16 __attribute__((ext_vector_type(16)));
typedef unsigned short u16;

#define INV4096F (1.0f/4096.0f)

// ---- ws byte offsets (total ~655 KB — round-1-proven footprint) ----
#define WS_E2    0u        // f32 [8192]        exact ||e||^2
#define WS_CAND  32768u    // u16 [16384][16]   top-2 per K-split (8 splits)
#define WS_IDX   557056u   // int [16384]
#define WS_HIST  622592u   // int [8192]
#define WS_LOSS  655360u   // f32 [1] (contiguous with hist for zeroing)

__global__ void vq_init(int* __restrict__ p, int n) {
    int i = blockIdx.x * 256 + threadIdx.x;
    if (i < n) p[i] = 0;
}

// exact ||emb_k||^2 from fp32
__global__ void vq_e2(const float* __restrict__ emb, float* __restrict__ e2) {
    const int tid  = threadIdx.x;
    const int lane = tid & 63;
    const int k    = blockIdx.x * 4 + (tid >> 6);
    float4 v = *(const float4*)&emb[k * D_ + lane * 4];
    float s = v.x*v.x + v.y*v.y + v.z*v.z + v.w*v.w;
    #pragma unroll
    for (int off = 32; off >= 1; off >>= 1) s += __shfl_down(s, off, 64);
    if (lane == 0) e2[k] = s;
}

// MFMA distance pass. grid = 1024: (row-tile of 128) x (K-split of 1024 codes).
// 4 blocks/CU (VGPR 124, LDS 32KB both allow exactly 4) -> 4 waves/SIMD TLP.
// In-kernel fp32->f16 hi/lo split; B staged via XOR-swizzled LDS (zero-conflict).
// dist = e2 - 2*(acc_hh + (acc_hl + acc_lh)/4096); exact-fp32 refine fixes tails.
__global__ __launch_bounds__(256, 1)
void vq_mfma(const float* __restrict__ z_e, const float* __restrict__ emb,
             const float* __restrict__ e2g, u16* __restrict__ cand)
{
    __shared__ char smem[32768];
    char*  BH = smem;                    // [32 codes][512B] halfs, swizzled
    char*  BL = smem + 16384;
    float* rd = (float*)smem;            // epilogue alias [128][32]
    int*   ri = (int*)(smem + 16384);

    const int tid = threadIdx.x;
    const int w   = tid >> 6;
    const int l   = tid & 63;
    const int lr  = l & 31;              // A row / B col within tile
    const int lg  = l >> 5;              // K-group (8 halfs each)
    const int rb  = blockIdx.x >> 3;
    const int ks  = blockIdx.x & 7;      // same-ks blocks stride-8 -> same XCD L2
    const int n0  = rb * 128;            // 128 | 1024 -> single b per tile
    const int b   = n0 >> 10;
    const int t0  = n0 & 1023;

    // ---- A fragments: load 128 x-values from z_e, split in regs ----
    f16x8 ah[16], al[16];
    {
        const float* xp = z_e + ((size_t)b * D_ + lg * 8) * T_ + t0 + w * 32 + lr;
        #pragma unroll
        for (int k8 = 0; k8 < 16; k8++) {
            #pragma unroll
            for (int u = 0; u < 8; u++) {
                float v = xp[(k8 * 16 + u) * T_];
                f16 h = (f16)v;
                ah[k8][u] = h;
                al[k8][u] = (f16)((v - (float)h) * 4096.0f);
            }
        }
    }

    float bst[16]; int bidx[16];
    #pragma unroll
    for (int i = 0; i < 16; i++) { bst[i] = 3.4e38f; bidx[i] = 0; }

    for (int ch = 0; ch < 32; ++ch) {
        const int k0 = ks * 1024 + ch * 32;
        __syncthreads();                  // previous chunk's LDS reads done
        // stage 32 codes x 256 d: fp32 -> hi/lo halfs, swizzled
        #pragma unroll
        for (int p = 0; p < 8; p++) {
            int u   = p * 256 + tid;      // float4 unit 0..2047
            int row = u >> 6;             // 0..31
            int q   = (u & 63) << 2;      // d offset 0..252
            float4 v = *(const float4*)&emb[(k0 + row) * D_ + q];
            f16x4 h, lo;
            h[0] = (f16)v.x; lo[0] = (f16)((v.x - (float)h[0]) * 4096.0f);
            h[1] = (f16)v.y; lo[1] = (f16)((v.y - (float)h[1]) * 4096.0f);
            h[2] = (f16)v.z; lo[2] = (f16)((v.z - (float)h[2]) * 4096.0f);
            h[3] = (f16)v.w; lo[3] = (f16)((v.w - (float)h[3]) * 4096.0f);
            int byteoff = row * 512 + (((q << 1)) ^ ((row & 31) << 4));
            *(f16x4*)(BH + byteoff) = h;
            *(f16x4*)(BL + byteoff) = lo;
        }
        float e2v = e2g[k0 + lr];
        __syncthreads();

        f32x16 acch, accl;
        #pragma unroll
        for (int i = 0; i < 16; i++) { acch[i] = 0.f; accl[i] = 0.f; }
        const int sb = lr * 512;
        #pragma unroll
        for (int k8 = 0; k8 < 16; k8++) {
            int off = (k8 * 32 + lg * 16) ^ ((lr & 31) << 4);
            f16x8 bh = *(const f16x8*)(BH + sb + off);
            f16x8 bl = *(const f16x8*)(BL + sb + off);
            acch = __builtin_amdgcn_mfma_f32_32x32x16_f16(ah[k8], bh, acch, 0, 0, 0);
            accl = __builtin_amdgcn_mfma_f32_32x32x16_f16(ah[k8], bl, accl, 0, 0, 0);
            accl = __builtin_amdgcn_mfma_f32_32x32x16_f16(al[k8], bh, accl, 0, 0, 0);
        }
        const int cc = k0 + lr;           // chunk ascending -> strict < keeps first-min
        #pragma unroll
        for (int i = 0; i < 16; i++) {
            float s    = fmaf(accl[i], INV4096F, acch[i]);
            float dist = fmaf(s, -2.0f, e2v);
            if (dist < bst[i]) { bst[i] = dist; bidx[i] = cc; }
        }
    }

    __syncthreads();
    // C/D layout (m74/m101): col=lane&31, row=(reg&3)+8*(reg>>2)+4*(lane>>5)
    #pragma unroll
    for (int i = 0; i < 16; i++) {
        int r = 4 * lg + (i & 3) + 8 * (i >> 2);
        rd[(w * 32 + r) * 32 + lr] = bst[i];
        ri[(w * 32 + r) * 32 + lr] = bidx[i];
    }
    __syncthreads();
    if (tid < 128) {
        float d1 = 3.4e38f, d2 = 3.4e38f; int i1 = 0x7fffffff, i2 = 0x7fffffff;
        for (int x = 0; x < 32; x++) {
            float dv = rd[tid * 32 + x]; int iv = ri[tid * 32 + x];
            if (dv < d1 || (dv == d1 && iv < i1)) { d2 = d1; i2 = i1; d1 = dv; i1 = iv; }
            else if (dv < d2 || (dv == d2 && iv < i2)) { d2 = dv; i2 = iv; }
        }
        int n = n0 + tid;
        cand[n * 16 + ks * 2]     = (u16)i1;
        cand[n * 16 + ks * 2 + 1] = (u16)i2;
    }
}

// exact fp32 re-rank of the 16 candidates per row -> final idx + hist
__global__ __launch_bounds__(256)
void vq_refine(const float* __restrict__ z_e, const float* __restrict__ emb,
               const float* __restrict__ e2g, const u16* __restrict__ cand,
               int* __restrict__ idx, int* __restrict__ hist)
{
    int g   = blockIdx.x * 256 + threadIdx.x;   // N_*16 threads
    int row = g >> 4;
    int j   = g & 15;
    int c   = cand[row * 16 + j];
    int b   = row >> 10;
    int t   = row & 1023;
    const float* xp = z_e + (size_t)b * D_ * T_ + t;
    const float* ep = emb + (size_t)c * D_;
    float s = 0.f;
    #pragma unroll 8
    for (int d = 0; d < D_; d++)
        s = fmaf(xp[(size_t)d * T_], ep[d], s);
    float dist = fmaf(s, -2.0f, e2g[c]);
    // reduce over the 16 candidate lanes (j=0..15 adjacent within the wave)
    #pragma unroll
    for (int off = 1; off <= 8; off <<= 1) {
        float od = __shfl_xor(dist, off, 64);
        int   oc = __shfl_xor(c,    off, 64);
        if (od < dist || (od == dist && oc < c)) { dist = od; c = oc; }
    }
    if (j == 0) {
        idx[row] = c;
        atomicAdd(&hist[c], 1);
    }
}

// gather z_q (exact fp32 emb), transposed out, commitment loss
__global__ __launch_bounds__(256)
void vq_gather(const float* __restrict__ z_e, const float* __restrict__ emb,
               const int* __restrict__ idx, float* __restrict__ out,
               float* __restrict__ lossAcc)
{
    __shared__ float es[64 * 259];
    __shared__ int   codes[64];
    __shared__ float red[4];
    const int tid = threadIdx.x;
    const int bb  = blockIdx.x >> 4;
    const int t0  = (blockIdx.x & 15) << 6;
    if (tid < 64) codes[tid] = idx[bb * T_ + t0 + tid];
    __syncthreads();
    for (int p = 0; p < 64; p++) {
        es[p * 259 + tid] = emb[codes[p] * D_ + tid];
    }
    __syncthreads();
    const int t  = tid & 63;
    const int ds = tid >> 6;
    float ls = 0.f;
    #pragma unroll 4
    for (int jj = 0; jj < 64; jj++) {
        int d = ds * 64 + jj;
        float e = es[t * 259 + d];
        int gi = (bb * D_ + d) * T_ + t0 + t;
        float x = z_e[gi];
        out[gi] = e;
        float df = e - x;
        ls += df * df;
    }
    #pragma unroll
    for (int off = 32; off >= 1; off >>= 1) ls += __shfl_down(ls, off, 64);
    if ((tid & 63) == 0) red[tid >> 6] = ls;
    __syncthreads();
    if (tid == 0) atomicAdd(lossAcc, red[0] + red[1] + red[2] + red[3]);
}

__global__ void vq_finalize(const int* __restrict__ hist, const float* __restrict__ lossAcc,
                            float* __restrict__ out_scalars)
{
    __shared__ float red[256];
    const int tid = threadIdx.x;
    float s = 0.f;
    for (int k = tid; k < K_; k += 256) {
        float p = (float)hist[k] * (1.0f / (float)N_);
        s += p * logf(p + 1e-10f);
    }
    red[tid] = s;
    __syncthreads();
    for (int off = 128; off >= 1; off >>= 1) {
        if (tid < off) red[tid] += red[tid + off];
        __syncthreads();
    }
    if (tid == 0) {
        out_scalars[0] = 0.25f * lossAcc[0] * (1.f / (float)(N_ * D_));
        out_scalars[1] = expf(-red[0]);
    }
}

extern "C" void kernel_launch(void* const* d_in, const int* in_sizes, int n_in,
                              void* d_out, int out_size, void* d_ws, size_t ws_size,
                              hipStream_t stream) {
    const float* z_e = (const float*)d_in[0];
    const float* emb = (const float*)d_in[1];
    float* out = (float*)d_out;
    char*  ws  = (char*)d_ws;

    float* e2      = (float*)(ws + WS_E2);
    u16*   cand    = (u16*)(ws + WS_CAND);
    int*   idx     = (int*)(ws + WS_IDX);
    int*   hist    = (int*)(ws + WS_HIST);
    float* lossAcc = (float*)(ws + WS_LOSS);

    vq_init    <<<33,   256, 0, stream>>>(hist, 8193);           // hist + lossAcc
    vq_e2      <<<2048, 256, 0, stream>>>(emb, e2);
    vq_mfma    <<<1024, 256, 0, stream>>>(z_e, emb, e2, cand);
    vq_refine  <<<1024, 256, 0, stream>>>(z_e, emb, e2, cand, idx, hist);
    vq_gather  <<<256,  256, 0, stream>>>(z_e, emb, idx, out, lossAcc);
    vq_finalize<<<1,    256, 0, stream>>>(hist, lossAcc, out + 4194304);
}

// Round 9
// 352.220 us; speedup vs baseline: 8.5542x; 1.1839x over previous
//
#include <hip/hip_runtime.h>
#include <math.h>

#define B_ 16
#define D_ 256
#define T_ 1024
#define K_ 8192
#define N_ (B_*T_)          // 16384 rows

typedef _Float16 f16;
typedef _Float16 f16x8 __attribute__((ext_vector_type(8)));
typedef float    f32x16 __attribute__((ext_vector_type(16)));
typedef unsigned short u16;

#define INV4096F (1.0f/4096.0f)

// ---- ws byte offsets (total ~655 KB — round-1-proven footprint) ----
#define WS_E2    0u        // f32 [8192]        exact ||e||^2
#define WS_CAND  32768u    // u16 [16384][16]   top-2 per K-split (8 splits)
#define WS_IDX   557056u   // int [16384]
#define WS_HIST  622592u   // int [8192]
#define WS_LOSS  655360u   // f32 [1] (contiguous with hist for zeroing)
// EH/EL (8 MB, f16, pre-swizzled) live in d_out[0..8MB) — overwritten later by vq_gather.

__device__ __forceinline__ void gload_lds16(const void* g, void* l) {
    __builtin_amdgcn_global_load_lds(
        (const __attribute__((address_space(1))) void*)g,
        (__attribute__((address_space(3))) void*)l, 16, 0, 0);
}

__global__ void vq_init(int* __restrict__ p, int n) {
    int i = blockIdx.x * 256 + threadIdx.x;
    if (i < n) p[i] = 0;
}

// emb fp32 -> EH/EL f16 hi/lo, PRE-SWIZZLED (16B-group g holds d-group g^(k&31)),
// so vq_mfma can stage with linear global_load_lds and read with the XOR pattern.
// Also computes exact ||e||^2 (fused, one emb pass).
__global__ __launch_bounds__(256)
void vq_prep(const float* __restrict__ emb, f16* __restrict__ EHs,
             f16* __restrict__ ELs, float* __restrict__ e2)
{
    const int tid = threadIdx.x;
    const int k   = blockIdx.x * 8 + (tid >> 5);   // 8 codes/block, 32 lanes/code
    const int g   = tid & 31;                      // 16B group within the 512B row
    const int d0  = (g ^ (k & 31)) * 8;            // pre-applied swizzle
    const float* src = emb + (size_t)k * D_ + d0;
    float4 a  = *(const float4*)src;
    float4 c4 = *(const float4*)(src + 4);
    float vals[8] = {a.x, a.y, a.z, a.w, c4.x, c4.y, c4.z, c4.w};
    f16x8 h, lo;
    float s = 0.f;
    #pragma unroll
    for (int u = 0; u < 8; u++) {
        float v = vals[u];
        f16 hh = (f16)v;
        h[u]  = hh;
        lo[u] = (f16)((v - (float)hh) * 4096.0f);
        s = fmaf(v, v, s);
    }
    *(f16x8*)(EHs + (size_t)k * D_ + g * 8) = h;
    *(f16x8*)(ELs + (size_t)k * D_ + g * 8) = lo;
    #pragma unroll
    for (int off = 1; off <= 16; off <<= 1) s += __shfl_xor(s, off, 64);
    if (g == 0) e2[k] = s;   // lanes 0 and 32 each write their code
}

// MFMA distance pass. grid = 1024: (row-tile of 128) x (K-split of 1024 codes).
// A: full-D x frags in regs (in-kernel fp32->f16 hi/lo split).
// B: pre-swizzled EH/EL staged via global_load_lds (async DMA, no VALU),
//    2-phase double-buffered LDS (2 x 32KB) — one barrier per chunk.
// dist = e2 - 2*(acc_hh + (acc_hl + acc_lh)/4096); exact-fp32 refine fixes tails.
__global__ __launch_bounds__(256, 1)
void vq_mfma(const float* __restrict__ z_e, const f16* __restrict__ EHs,
             const f16* __restrict__ ELs, const float* __restrict__ e2g,
             u16* __restrict__ cand)
{
    __shared__ char smem[65536];         // 2 x (BH 16KB | BL 16KB)
    float* rd = (float*)smem;            // epilogue alias [128][32]
    int*   ri = (int*)(smem + 16384);

    const int tid = threadIdx.x;
    const int w   = tid >> 6;
    const int l   = tid & 63;
    const int lr  = l & 31;              // A row / B col within tile
    const int lg  = l >> 5;              // K-group (8 halfs each)
    const int rb  = blockIdx.x >> 3;
    const int ks  = blockIdx.x & 7;      // same-ks blocks stride-8 -> same XCD L2
    const int n0  = rb * 128;            // 128 | 1024 -> single b per tile
    const int b   = n0 >> 10;
    const int t0  = n0 & 1023;

    // ---- A fragments: load 128 x-values from z_e, split in regs ----
    f16x8 ah[16], al[16];
    {
        const float* xp = z_e + ((size_t)b * D_ + lg * 8) * T_ + t0 + w * 32 + lr;
        #pragma unroll
        for (int k8 = 0; k8 < 16; k8++) {
            #pragma unroll
            for (int u = 0; u < 8; u++) {
                float v = xp[(k8 * 16 + u) * T_];
                f16 h = (f16)v;
                ah[k8][u] = h;
                al[k8][u] = (f16)((v - (float)h) * 4096.0f);
            }
        }
    }

    float bst[16]; int bidx[16];
    #pragma unroll
    for (int i = 0; i < 16; i++) { bst[i] = 3.4e38f; bidx[i] = 0; }

    const char* EHb = (const char*)EHs;
    const char* ELb = (const char*)ELs;

    // async stage of one 32-code chunk (16KB H + 16KB L) into buffer `bs`
    #define STAGE(bs, kk0) {                                                  \
        char* dH = smem + (bs) * 32768;                                       \
        char* dL = dH + 16384;                                                \
        const char* sH = EHb + (size_t)(kk0) * 512;                           \
        const char* sL = ELb + (size_t)(kk0) * 512;                           \
        _Pragma("unroll")                                                     \
        for (int p = 0; p < 4; p++) {                                         \
            gload_lds16(sH + p * 4096 + tid * 16, dH + p * 4096 + tid * 16);  \
            gload_lds16(sL + p * 4096 + tid * 16, dL + p * 4096 + tid * 16);  \
        }                                                                     \
    }

    STAGE(0, ks * 1024);
    __syncthreads();                      // compiler drains vmcnt before barrier

    for (int ch = 0; ch < 32; ++ch) {
        const int cur = ch & 1;
        if (ch < 31) STAGE(cur ^ 1, ks * 1024 + (ch + 1) * 32);  // async prefetch
        const int k0 = ks * 1024 + ch * 32;
        const float e2v = e2g[k0 + lr];
        const char* BHc = smem + cur * 32768;

        f32x16 acch, accl;
        #pragma unroll
        for (int i = 0; i < 16; i++) { acch[i] = 0.f; accl[i] = 0.f; }
        const int sb = lr * 512;
        #pragma unroll
        for (int k8 = 0; k8 < 16; k8++) {
            int off = (k8 * 32 + lg * 16) ^ ((lr & 31) << 4);
            f16x8 bh = *(const f16x8*)(BHc + sb + off);
            f16x8 bl = *(const f16x8*)(BHc + 16384 + sb + off);
            acch = __builtin_amdgcn_mfma_f32_32x32x16_f16(ah[k8], bh, acch, 0, 0, 0);
            accl = __builtin_amdgcn_mfma_f32_32x32x16_f16(ah[k8], bl, accl, 0, 0, 0);
            accl = __builtin_amdgcn_mfma_f32_32x32x16_f16(al[k8], bh, accl, 0, 0, 0);
        }
        const int cc = k0 + lr;           // chunk ascending -> strict < keeps first-min
        #pragma unroll
        for (int i = 0; i < 16; i++) {
            float s    = fmaf(accl[i], INV4096F, acch[i]);
            float dist = fmaf(s, -2.0f, e2v);
            if (dist < bst[i]) { bst[i] = dist; bidx[i] = cc; }
        }
        __syncthreads();                  // drains vmcnt(stage ch+1) + lgkm(reads)
    }

    // C/D layout (m74/m101): col=lane&31, row=(reg&3)+8*(reg>>2)+4*(lane>>5)
    #pragma unroll
    for (int i = 0; i < 16; i++) {
        int r = 4 * lg + (i & 3) + 8 * (i >> 2);
        rd[(w * 32 + r) * 32 + lr] = bst[i];
        ri[(w * 32 + r) * 32 + lr] = bidx[i];
    }
    __syncthreads();
    if (tid < 128) {
        float d1 = 3.4e38f, d2 = 3.4e38f; int i1 = 0x7fffffff, i2 = 0x7fffffff;
        for (int x = 0; x < 32; x++) {
            float dv = rd[tid * 32 + x]; int iv = ri[tid * 32 + x];
            if (dv < d1 || (dv == d1 && iv < i1)) { d2 = d1; i2 = i1; d1 = dv; i1 = iv; }
            else if (dv < d2 || (dv == d2 && iv < i2)) { d2 = dv; i2 = iv; }
        }
        int n = n0 + tid;
        cand[n * 16 + ks * 2]     = (u16)i1;
        cand[n * 16 + ks * 2 + 1] = (u16)i2;
    }
    #undef STAGE
}

// exact fp32 re-rank of the 16 candidates per row.
// One wave per row: x staged once to LDS (no 16x redundant strided reads),
// 4 lanes per candidate (lane = cand*4 + quarter).
__global__ __launch_bounds__(256)
void vq_refine(const float* __restrict__ z_e, const float* __restrict__ emb,
               const float* __restrict__ e2g, const u16* __restrict__ cand,
               int* __restrict__ idx, int* __restrict__ hist)
{
    __shared__ float xsh[4][264];        // [wave][quarter*65 + d] (65: bank-spread)
    const int tid = threadIdx.x;
    const int w   = tid >> 6;
    const int l   = tid & 63;
    const int row = blockIdx.x * 4 + w;
    const int b   = row >> 10;
    const int t   = row & 1023;
    #pragma unroll
    for (int q = 0; q < 4; q++)
        xsh[w][q * 65 + l] = z_e[(size_t)(b * D_ + q * 64 + l) * T_ + t];
    __syncthreads();
    const int j  = l >> 2;               // candidate 0..15
    const int qd = l & 3;                // d-quarter
    int c = cand[row * 16 + j];
    const float* ep = emb + (size_t)c * D_ + qd * 64;
    const float* xq = &xsh[w][qd * 65];
    float s = 0.f;
    #pragma unroll
    for (int d = 0; d < 64; d += 4) {
        float4 e4 = *(const float4*)(ep + d);
        s = fmaf(xq[d],     e4.x, s);
        s = fmaf(xq[d + 1], e4.y, s);
        s = fmaf(xq[d + 2], e4.z, s);
        s = fmaf(xq[d + 3], e4.w, s);
    }
    s += __shfl_xor(s, 1, 64);
    s += __shfl_xor(s, 2, 64);           // all 4 lanes now hold the full dot
    float dist = fmaf(s, -2.0f, e2g[c]);
    #pragma unroll
    for (int off = 4; off <= 32; off <<= 1) {
        float od = __shfl_xor(dist, off, 64);
        int   oc = __shfl_xor(c,    off, 64);
        if (od < dist || (od == dist && oc < c)) { dist = od; c = oc; }
    }
    if (l == 0) {
        idx[row] = c;
        atomicAdd(&hist[c], 1);
    }
}

// gather z_q (exact fp32 emb), transposed out, commitment loss
__global__ __launch_bounds__(256)
void vq_gather(const float* __restrict__ z_e, const float* __restrict__ emb,
               const int* __restrict__ idx, float* __restrict__ out,
               float* __restrict__ lossAcc)
{
    __shared__ float es[64 * 259];
    __shared__ int   codes[64];
    __shared__ float red[4];
    const int tid = threadIdx.x;
    const int bb  = blockIdx.x >> 4;
    const int t0  = (blockIdx.x & 15) << 6;
    if (tid < 64) codes[tid] = idx[bb * T_ + t0 + tid];
    __syncthreads();
    for (int p = 0; p < 64; p++) {
        es[p * 259 + tid] = emb[codes[p] * D_ + tid];
    }
    __syncthreads();
    const int t  = tid & 63;
    const int ds = tid >> 6;
    float ls = 0.f;
    #pragma unroll 4
    for (int jj = 0; jj < 64; jj++) {
        int d = ds * 64 + jj;
        float e = es[t * 259 + d];
        int gi = (bb * D_ + d) * T_ + t0 + t;
        float x = z_e[gi];
        out[gi] = e;
        float df = e - x;
        ls += df * df;
    }
    #pragma unroll
    for (int off = 32; off >= 1; off >>= 1) ls += __shfl_down(ls, off, 64);
    if ((tid & 63) == 0) red[tid >> 6] = ls;
    __syncthreads();
    if (tid == 0) atomicAdd(lossAcc, red[0] + red[1] + red[2] + red[3]);
}

__global__ void vq_finalize(const int* __restrict__ hist, const float* __restrict__ lossAcc,
                            float* __restrict__ out_scalars)
{
    __shared__ float red[256];
    const int tid = threadIdx.x;
    float s = 0.f;
    for (int k = tid; k < K_; k += 256) {
        float p = (float)hist[k] * (1.0f / (float)N_);
        s += p * logf(p + 1e-10f);
    }
    red[tid] = s;
    __syncthreads();
    for (int off = 128; off >= 1; off >>= 1) {
        if (tid < off) red[tid] += red[tid + off];
        __syncthreads();
    }
    if (tid == 0) {
        out_scalars[0] = 0.25f * lossAcc[0] * (1.f / (float)(N_ * D_));
        out_scalars[1] = expf(-red[0]);
    }
}

extern "C" void kernel_launch(void* const* d_in, const int* in_sizes, int n_in,
                              void* d_out, int out_size, void* d_ws, size_t ws_size,
                              hipStream_t stream) {
    const float* z_e = (const float*)d_in[0];
    const float* emb = (const float*)d_in[1];
    float* out = (float*)d_out;
    char*  ws  = (char*)d_ws;

    float* e2      = (float*)(ws + WS_E2);
    u16*   cand    = (u16*)(ws + WS_CAND);
    int*   idx     = (int*)(ws + WS_IDX);
    int*   hist    = (int*)(ws + WS_HIST);
    float* lossAcc = (float*)(ws + WS_LOSS);

    // EH/EL (pre-swizzled f16 splits) live in d_out's first 8MB; vq_gather
    // overwrites that region afterwards (stream-ordered, graph-safe).
    f16* EHs = (f16*)d_out;
    f16* ELs = EHs + 2097152;            // byte offset 4MB

    vq_init    <<<33,   256, 0, stream>>>(hist, 8193);           // hist + lossAcc
    vq_prep    <<<1024, 256, 0, stream>>>(emb, EHs, ELs, e2);
    vq_mfma    <<<1024, 256, 0, stream>>>(z_e, EHs, ELs, e2, cand);
    vq_refine  <<<4096, 256, 0, stream>>>(z_e, emb, e2, cand, idx, hist);
    vq_gather  <<<256,  256, 0, stream>>>(z_e, emb, idx, out, lossAcc);
    vq_finalize<<<1,    256, 0, stream>>>(hist, lossAcc, out + 4194304);
}

// Round 10
// 292.042 us; speedup vs baseline: 10.3169x; 1.2061x over previous
//
#include <hip/hip_runtime.h>
#include <math.h>

#define B_ 16
#define D_ 256
#define T_ 1024
#define K_ 8192
#define N_ (B_*T_)          // 16384 rows

typedef _Float16 f16;
typedef _Float16 f16x8 __attribute__((ext_vector_type(8)));
typedef float    f32x16 __attribute__((ext_vector_type(16)));
typedef unsigned short u16;

#define INV4096F (1.0f/4096.0f)

// ---- ws byte offsets (total ~655 KB — round-1-proven footprint) ----
#define WS_E2    0u        // f32 [8192]        exact ||e||^2
#define WS_CAND  32768u    // u16 [16384][16]   top-2 per K-split (8 splits)
#define WS_IDX   557056u   // int [16384]
#define WS_HIST  622592u   // int [8192]
#define WS_LOSS  655360u   // f32 [1] (contiguous with hist for zeroing)
// EH (4 MB, f16 hi, pre-swizzled) lives in d_out[0..4MB) — overwritten by vq_gather.

__device__ __forceinline__ void gload_lds16(const void* g, void* l) {
    __builtin_amdgcn_global_load_lds(
        (const __attribute__((address_space(1))) void*)g,
        (__attribute__((address_space(3))) void*)l, 16, 0, 0);
}

// emb fp32 -> EH f16 hi, PRE-SWIZZLED (16B-group g holds d-group g^(k&31)),
// so vq_mfma stages with linear global_load_lds and reads with the XOR pattern.
// Fused: exact ||e||^2, and hist/loss zeroing (blocks 0..32).
__global__ __launch_bounds__(256)
void vq_prep(const float* __restrict__ emb, f16* __restrict__ EHs,
             float* __restrict__ e2, int* __restrict__ histz)
{
    const int tid = threadIdx.x;
    if (blockIdx.x < 33) {                         // zero hist + lossAcc (8193 ints)
        int i = blockIdx.x * 256 + tid;
        if (i < 8193) histz[i] = 0;
    }
    const int k   = blockIdx.x * 8 + (tid >> 5);   // 8 codes/block, 32 lanes/code
    const int g   = tid & 31;                      // 16B group within the 512B row
    const int d0  = (g ^ (k & 31)) * 8;            // pre-applied swizzle
    const float* src = emb + (size_t)k * D_ + d0;
    float4 a  = *(const float4*)src;
    float4 c4 = *(const float4*)(src + 4);
    float vals[8] = {a.x, a.y, a.z, a.w, c4.x, c4.y, c4.z, c4.w};
    f16x8 h;
    float s = 0.f;
    #pragma unroll
    for (int u = 0; u < 8; u++) {
        float v = vals[u];
        h[u] = (f16)v;
        s = fmaf(v, v, s);
    }
    *(f16x8*)(EHs + (size_t)k * D_ + g * 8) = h;
    #pragma unroll
    for (int off = 1; off <= 16; off <<= 1) s += __shfl_xor(s, off, 64);
    if (g == 0) e2[k] = s;   // lanes 0 and 32 each write their code
}

// MFMA distance pass. grid = 1024: (row-tile of 128) x (K-split of 1024 codes).
// A: full-D x hi/lo frags in regs (in-kernel fp32->f16 split — x-side lo KEPT).
// B: f16 hi only (e-side lo dropped: dist-err sigma ~9e-3 << top-2 safety net),
//    staged via global_load_lds into 2 x 16KB double-buffered LDS -> 4 blocks/CU.
// dist = e2 - 2*(acc_hh + acc_lh/4096); exact-fp32 16-cand refine fixes tails.
__global__ __launch_bounds__(256, 1)
void vq_mfma(const float* __restrict__ z_e, const f16* __restrict__ EHs,
             const float* __restrict__ e2g, u16* __restrict__ cand)
{
    __shared__ char smem[32768];         // 2 x 16KB B-buffers; epilogue alias
    float* rd = (float*)smem;            // [128][32]
    int*   ri = (int*)(smem + 16384);

    const int tid = threadIdx.x;
    const int w   = tid >> 6;
    const int l   = tid & 63;
    const int lr  = l & 31;              // A row / B col within tile
    const int lg  = l >> 5;              // K-group (8 halfs each)
    const int rb  = blockIdx.x >> 3;
    const int ks  = blockIdx.x & 7;      // same-ks blocks stride-8 -> same XCD L2
    const int n0  = rb * 128;            // 128 | 1024 -> single b per tile
    const int b   = n0 >> 10;
    const int t0  = n0 & 1023;

    // ---- A fragments: load 128 x-values from z_e, split hi/lo in regs ----
    f16x8 ah[16], al[16];
    {
        const float* xp = z_e + ((size_t)b * D_ + lg * 8) * T_ + t0 + w * 32 + lr;
        #pragma unroll
        for (int k8 = 0; k8 < 16; k8++) {
            #pragma unroll
            for (int u = 0; u < 8; u++) {
                float v = xp[(k8 * 16 + u) * T_];
                f16 h = (f16)v;
                ah[k8][u] = h;
                al[k8][u] = (f16)((v - (float)h) * 4096.0f);
            }
        }
    }

    float bst[16]; int bidx[16];
    #pragma unroll
    for (int i = 0; i < 16; i++) { bst[i] = 3.4e38f; bidx[i] = 0; }

    const char* EHb = (const char*)EHs;

    // async stage of one 32-code chunk (16KB) into buffer `bs`
    #define STAGE(bs, kk0) {                                                  \
        char* dH = smem + (bs) * 16384;                                       \
        const char* sH = EHb + (size_t)(kk0) * 512;                           \
        _Pragma("unroll")                                                     \
        for (int p = 0; p < 4; p++) {                                         \
            gload_lds16(sH + p * 4096 + tid * 16, dH + p * 4096 + tid * 16);  \
        }                                                                     \
    }

    STAGE(0, ks * 1024);
    __syncthreads();                      // compiler drains vmcnt before barrier

    for (int ch = 0; ch < 32; ++ch) {
        const int cur = ch & 1;
        if (ch < 31) STAGE(cur ^ 1, ks * 1024 + (ch + 1) * 32);  // async prefetch
        const int k0 = ks * 1024 + ch * 32;
        const float e2v = e2g[k0 + lr];
        const char* BHc = smem + cur * 16384;

        f32x16 acch, accl;
        #pragma unroll
        for (int i = 0; i < 16; i++) { acch[i] = 0.f; accl[i] = 0.f; }
        const int sb = lr * 512;
        #pragma unroll
        for (int k8 = 0; k8 < 16; k8++) {
            int off = (k8 * 32 + lg * 16) ^ ((lr & 31) << 4);
            f16x8 bh = *(const f16x8*)(BHc + sb + off);
            acch = __builtin_amdgcn_mfma_f32_32x32x16_f16(ah[k8], bh, acch, 0, 0, 0);
            accl = __builtin_amdgcn_mfma_f32_32x32x16_f16(al[k8], bh, accl, 0, 0, 0);
        }
        const int cc = k0 + lr;           // chunk ascending -> strict < keeps first-min
        #pragma unroll
        for (int i = 0; i < 16; i++) {
            float s    = fmaf(accl[i], INV4096F, acch[i]);
            float dist = fmaf(s, -2.0f, e2v);
            if (dist < bst[i]) { bst[i] = dist; bidx[i] = cc; }
        }
        __syncthreads();                  // drains vmcnt(stage ch+1) + lgkm(reads)
    }

    // C/D layout (m74/m101): col=lane&31, row=(reg&3)+8*(reg>>2)+4*(lane>>5)
    #pragma unroll
    for (int i = 0; i < 16; i++) {
        int r = 4 * lg + (i & 3) + 8 * (i >> 2);
        rd[(w * 32 + r) * 32 + lr] = bst[i];
        ri[(w * 32 + r) * 32 + lr] = bidx[i];
    }
    __syncthreads();
    if (tid < 128) {
        float d1 = 3.4e38f, d2 = 3.4e38f; int i1 = 0x7fffffff, i2 = 0x7fffffff;
        for (int x = 0; x < 32; x++) {
            float dv = rd[tid * 32 + x]; int iv = ri[tid * 32 + x];
            if (dv < d1 || (dv == d1 && iv < i1)) { d2 = d1; i2 = i1; d1 = dv; i1 = iv; }
            else if (dv < d2 || (dv == d2 && iv < i2)) { d2 = dv; i2 = iv; }
        }
        int n = n0 + tid;
        cand[n * 16 + ks * 2]     = (u16)i1;
        cand[n * 16 + ks * 2 + 1] = (u16)i2;
    }
    #undef STAGE
}

// exact fp32 re-rank of the 16 candidates per row.
// One wave per row: x staged once to LDS, 4 lanes per candidate.
__global__ __launch_bounds__(256)
void vq_refine(const float* __restrict__ z_e, const float* __restrict__ emb,
               const float* __restrict__ e2g, const u16* __restrict__ cand,
               int* __restrict__ idx, int* __restrict__ hist)
{
    __shared__ float xsh[4][264];        // [wave][quarter*65 + d] (65: bank-spread)
    const int tid = threadIdx.x;
    const int w   = tid >> 6;
    const int l   = tid & 63;
    const int row = blockIdx.x * 4 + w;
    const int b   = row >> 10;
    const int t   = row & 1023;
    #pragma unroll
    for (int q = 0; q < 4; q++)
        xsh[w][q * 65 + l] = z_e[(size_t)(b * D_ + q * 64 + l) * T_ + t];
    __syncthreads();
    const int j  = l >> 2;               // candidate 0..15
    const int qd = l & 3;                // d-quarter
    int c = cand[row * 16 + j];
    const float* ep = emb + (size_t)c * D_ + qd * 64;
    const float* xq = &xsh[w][qd * 65];
    float s = 0.f;
    #pragma unroll
    for (int d = 0; d < 64; d += 4) {
        float4 e4 = *(const float4*)(ep + d);
        s = fmaf(xq[d],     e4.x, s);
        s = fmaf(xq[d + 1], e4.y, s);
        s = fmaf(xq[d + 2], e4.z, s);
        s = fmaf(xq[d + 3], e4.w, s);
    }
    s += __shfl_xor(s, 1, 64);
    s += __shfl_xor(s, 2, 64);           // all 4 lanes now hold the full dot
    float dist = fmaf(s, -2.0f, e2g[c]);
    #pragma unroll
    for (int off = 4; off <= 32; off <<= 1) {
        float od = __shfl_xor(dist, off, 64);
        int   oc = __shfl_xor(c,    off, 64);
        if (od < dist || (od == dist && oc < c)) { dist = od; c = oc; }
    }
    if (l == 0) {
        idx[row] = c;
        atomicAdd(&hist[c], 1);
    }
}

// gather z_q (exact fp32 emb), transposed out, commitment loss
__global__ __launch_bounds__(256)
void vq_gather(const float* __restrict__ z_e, const float* __restrict__ emb,
               const int* __restrict__ idx, float* __restrict__ out,
               float* __restrict__ lossAcc)
{
    __shared__ float es[64 * 259];
    __shared__ int   codes[64];
    __shared__ float red[4];
    const int tid = threadIdx.x;
    const int bb  = blockIdx.x >> 4;
    const int t0  = (blockIdx.x & 15) << 6;
    if (tid < 64) codes[tid] = idx[bb * T_ + t0 + tid];
    __syncthreads();
    for (int p = 0; p < 64; p++) {
        es[p * 259 + tid] = emb[codes[p] * D_ + tid];
    }
    __syncthreads();
    const int t  = tid & 63;
    const int ds = tid >> 6;
    float ls = 0.f;
    #pragma unroll 4
    for (int jj = 0; jj < 64; jj++) {
        int d = ds * 64 + jj;
        float e = es[t * 259 + d];
        int gi = (bb * D_ + d) * T_ + t0 + t;
        float x = z_e[gi];
        out[gi] = e;
        float df = e - x;
        ls += df * df;
    }
    #pragma unroll
    for (int off = 32; off >= 1; off >>= 1) ls += __shfl_down(ls, off, 64);
    if ((tid & 63) == 0) red[tid >> 6] = ls;
    __syncthreads();
    if (tid == 0) atomicAdd(lossAcc, red[0] + red[1] + red[2] + red[3]);
}

__global__ void vq_finalize(const int* __restrict__ hist, const float* __restrict__ lossAcc,
                            float* __restrict__ out_scalars)
{
    __shared__ float red[256];
    const int tid = threadIdx.x;
    float s = 0.f;
    for (int k = tid; k < K_; k += 256) {
        float p = (float)hist[k] * (1.0f / (float)N_);
        s += p * logf(p + 1e-10f);
    }
    red[tid] = s;
    __syncthreads();
    for (int off = 128; off >= 1; off >>= 1) {
        if (tid < off) red[tid] += red[tid + off];
        __syncthreads();
    }
    if (tid == 0) {
        out_scalars[0] = 0.25f * lossAcc[0] * (1.f / (float)(N_ * D_));
        out_scalars[1] = expf(-red[0]);
    }
}

extern "C" void kernel_launch(void* const* d_in, const int* in_sizes, int n_in,
                              void* d_out, int out_size, void* d_ws, size_t ws_size,
                              hipStream_t stream) {
    const float* z_e = (const float*)d_in[0];
    const float* emb = (const float*)d_in[1];
    float* out = (float*)d_out;
    char*  ws  = (char*)d_ws;

    float* e2      = (float*)(ws + WS_E2);
    u16*   cand    = (u16*)(ws + WS_CAND);
    int*   idx     = (int*)(ws + WS_IDX);
    int*   hist    = (int*)(ws + WS_HIST);
    float* lossAcc = (float*)(ws + WS_LOSS);

    // EH (pre-swizzled f16 hi) lives in d_out's first 4MB; vq_gather
    // overwrites the whole region afterwards (stream-ordered, graph-safe).
    f16* EHs = (f16*)d_out;

    vq_prep    <<<1024, 256, 0, stream>>>(emb, EHs, e2, hist);   // + hist/loss zero
    vq_mfma    <<<1024, 256, 0, stream>>>(z_e, EHs, e2, cand);
    vq_refine  <<<4096, 256, 0, stream>>>(z_e, emb, e2, cand, idx, hist);
    vq_gather  <<<256,  256, 0, stream>>>(z_e, emb, idx, out, lossAcc);
    vq_finalize<<<1,    256, 0, stream>>>(hist, lossAcc, out + 4194304);
}

// Round 11
// 228.487 us; speedup vs baseline: 13.1866x; 1.2782x over previous
//
#include <hip/hip_runtime.h>
#include <math.h>

#define B_ 16
#define D_ 256
#define T_ 1024
#define K_ 8192
#define N_ (B_*T_)          // 16384 rows

typedef _Float16 f16;
typedef _Float16 f16x8 __attribute__((ext_vector_type(8)));
typedef float    f32x16 __attribute__((ext_vector_type(16)));
typedef unsigned short u16;

// ---- ws byte offsets (total ~655 KB — round-1-proven footprint) ----
#define WS_E2    0u        // f32 [8192]        exact ||e||^2
#define WS_CAND  32768u    // u16 [16384][16]   top-2 per K-split (8 splits)
#define WS_IDX   557056u   // int [16384]
#define WS_HIST  622592u   // int [8192]
#define WS_LOSS  655360u   // f32 [1] (contiguous with hist for zeroing)
// EH (4 MB, f16 hi, pre-swizzled) lives in d_out[0..4MB) — overwritten by vq_gather.

__device__ __forceinline__ void gload_lds16(const void* g, void* l) {
    __builtin_amdgcn_global_load_lds(
        (const __attribute__((address_space(1))) void*)g,
        (__attribute__((address_space(3))) void*)l, 16, 0, 0);
}

// emb fp32 -> EH f16 hi, PRE-SWIZZLED (16B-group g holds d-group g^(k&31)),
// so vq_mfma stages with linear global_load_lds and reads with the XOR pattern.
// Fused: exact ||e||^2, and hist/loss zeroing (blocks 0..32).
__global__ __launch_bounds__(256)
void vq_prep(const float* __restrict__ emb, f16* __restrict__ EHs,
             float* __restrict__ e2, int* __restrict__ histz)
{
    const int tid = threadIdx.x;
    if (blockIdx.x < 33) {                         // zero hist + lossAcc (8193 ints)
        int i = blockIdx.x * 256 + tid;
        if (i < 8193) histz[i] = 0;
    }
    const int k   = blockIdx.x * 8 + (tid >> 5);   // 8 codes/block, 32 lanes/code
    const int g   = tid & 31;                      // 16B group within the 512B row
    const int d0  = (g ^ (k & 31)) * 8;            // pre-applied swizzle
    const float* src = emb + (size_t)k * D_ + d0;
    float4 a  = *(const float4*)src;
    float4 c4 = *(const float4*)(src + 4);
    float vals[8] = {a.x, a.y, a.z, a.w, c4.x, c4.y, c4.z, c4.w};
    f16x8 h;
    float s = 0.f;
    #pragma unroll
    for (int u = 0; u < 8; u++) {
        float v = vals[u];
        h[u] = (f16)v;
        s = fmaf(v, v, s);
    }
    *(f16x8*)(EHs + (size_t)k * D_ + g * 8) = h;
    #pragma unroll
    for (int off = 1; off <= 16; off <<= 1) s += __shfl_xor(s, off, 64);
    if (g == 0) e2[k] = s;   // lanes 0 and 32 each write their code
}

// MFMA distance pass. grid = 1024: (row-tile of 128) x (K-split of 1024 codes).
// SINGLE-TERM f16-hi (x-lo and e-lo both dropped: combined dist-err sigma
// ~1.3e-2, zero flips observed at 9e-3 in r9/r10; exact-fp32 16-cand refine +
// ~25-abs output threshold give layered slack). 16 MFMA + 16 ds_read_b128 per
// chunk per wave; B staged via global_load_lds, 2 x 16KB double-buffer.
__global__ __launch_bounds__(256, 1)
void vq_mfma(const float* __restrict__ z_e, const f16* __restrict__ EHs,
             const float* __restrict__ e2g, u16* __restrict__ cand)
{
    __shared__ char smem[32768];         // 2 x 16KB B-buffers; epilogue alias
    float* rd = (float*)smem;            // [128][32]
    int*   ri = (int*)(smem + 16384);

    const int tid = threadIdx.x;
    const int w   = tid >> 6;
    const int l   = tid & 63;
    const int lr  = l & 31;              // A row / B col within tile
    const int lg  = l >> 5;              // K-group (8 halfs each)
    const int rb  = blockIdx.x >> 3;
    const int ks  = blockIdx.x & 7;      // same-ks blocks stride-8 -> same XCD L2
    const int n0  = rb * 128;            // 128 | 1024 -> single b per tile
    const int b   = n0 >> 10;
    const int t0  = n0 & 1023;

    // ---- A fragments: load 128 x-values from z_e, convert to f16 hi ----
    f16x8 ah[16];
    {
        const float* xp = z_e + ((size_t)b * D_ + lg * 8) * T_ + t0 + w * 32 + lr;
        #pragma unroll
        for (int k8 = 0; k8 < 16; k8++) {
            #pragma unroll
            for (int u = 0; u < 8; u++) {
                ah[k8][u] = (f16)xp[(k8 * 16 + u) * T_];
            }
        }
    }

    float bst[16]; int bidx[16];
    #pragma unroll
    for (int i = 0; i < 16; i++) { bst[i] = 3.4e38f; bidx[i] = 0; }

    const char* EHb = (const char*)EHs;

    // async stage of one 32-code chunk (16KB) into buffer `bs`
    #define STAGE(bs, kk0) {                                                  \
        char* dH = smem + (bs) * 16384;                                       \
        const char* sH = EHb + (size_t)(kk0) * 512;                           \
        _Pragma("unroll")                                                     \
        for (int p = 0; p < 4; p++) {                                         \
            gload_lds16(sH + p * 4096 + tid * 16, dH + p * 4096 + tid * 16);  \
        }                                                                     \
    }

    STAGE(0, ks * 1024);
    __syncthreads();                      // compiler drains vmcnt before barrier

    for (int ch = 0; ch < 32; ++ch) {
        const int cur = ch & 1;
        if (ch < 31) STAGE(cur ^ 1, ks * 1024 + (ch + 1) * 32);  // async prefetch
        const int k0 = ks * 1024 + ch * 32;
        const float e2v = e2g[k0 + lr];
        const char* BHc = smem + cur * 16384;

        f32x16 acch;
        #pragma unroll
        for (int i = 0; i < 16; i++) acch[i] = 0.f;
        const int sb = lr * 512;
        #pragma unroll
        for (int k8 = 0; k8 < 16; k8++) {
            int off = (k8 * 32 + lg * 16) ^ ((lr & 31) << 4);
            f16x8 bh = *(const f16x8*)(BHc + sb + off);
            acch = __builtin_amdgcn_mfma_f32_32x32x16_f16(ah[k8], bh, acch, 0, 0, 0);
        }
        const int cc = k0 + lr;           // chunk ascending -> strict < keeps first-min
        #pragma unroll
        for (int i = 0; i < 16; i++) {
            float dist = fmaf(acch[i], -2.0f, e2v);
            if (dist < bst[i]) { bst[i] = dist; bidx[i] = cc; }
        }
        __syncthreads();                  // drains vmcnt(stage ch+1) + lgkm(reads)
    }

    // C/D layout (m74/m101): col=lane&31, row=(reg&3)+8*(reg>>2)+4*(lane>>5)
    #pragma unroll
    for (int i = 0; i < 16; i++) {
        int r = 4 * lg + (i & 3) + 8 * (i >> 2);
        rd[(w * 32 + r) * 32 + lr] = bst[i];
        ri[(w * 32 + r) * 32 + lr] = bidx[i];
    }
    __syncthreads();
    if (tid < 128) {
        float d1 = 3.4e38f, d2 = 3.4e38f; int i1 = 0x7fffffff, i2 = 0x7fffffff;
        for (int x = 0; x < 32; x++) {
            float dv = rd[tid * 32 + x]; int iv = ri[tid * 32 + x];
            if (dv < d1 || (dv == d1 && iv < i1)) { d2 = d1; i2 = i1; d1 = dv; i1 = iv; }
            else if (dv < d2 || (dv == d2 && iv < i2)) { d2 = dv; i2 = iv; }
        }
        int n = n0 + tid;
        cand[n * 16 + ks * 2]     = (u16)i1;
        cand[n * 16 + ks * 2 + 1] = (u16)i2;
    }
    #undef STAGE
}

// exact fp32 re-rank of the 16 candidates per row.
// Block = 32 consecutive rows (same b); x staged to LDS with lane-contiguous
// coalesced reads (the old version's stride-4KB z_e gather was the cost).
// Each wave then handles 8 rows; per row: 16 cands x 4 d-quarter lanes;
// x-reads are 16-lane LDS broadcasts.
__global__ __launch_bounds__(256)
void vq_refine(const float* __restrict__ z_e, const float* __restrict__ emb,
               const float* __restrict__ e2g, const u16* __restrict__ cand,
               int* __restrict__ idx, int* __restrict__ hist)
{
    __shared__ float xsh[32][260];       // row stride 1040B (16B-aligned, odd/16)
    const int tid = threadIdx.x;
    const int n0  = blockIdx.x * 32;     // 32 | 1024 -> single b
    const int b   = n0 >> 10;
    const int t0  = n0 & 1023;
    // stage 32 rows x 256 d: lane-contiguous in t (128B segments)
    {
        const int t    = tid & 31;
        const int dcol = tid >> 5;       // 0..7
        #pragma unroll
        for (int p = 0; p < 32; p++) {
            int d = p * 8 + dcol;
            xsh[t][d] = z_e[(size_t)(b * D_ + d) * T_ + t0 + t];
        }
    }
    __syncthreads();
    const int w  = tid >> 6;
    const int l  = tid & 63;
    const int j  = l >> 2;               // candidate 0..15
    const int qd = l & 3;                // d-quarter
    for (int it = 0; it < 8; ++it) {
        const int r   = w * 8 + it;      // row within block
        const int row = n0 + r;
        int c = cand[row * 16 + j];
        const float* ep = emb + (size_t)c * D_ + qd * 64;
        const float* xq = &xsh[r][qd * 64];
        float s = 0.f;
        #pragma unroll
        for (int d = 0; d < 64; d += 4) {
            float4 e4 = *(const float4*)(ep + d);
            s = fmaf(xq[d],     e4.x, s);
            s = fmaf(xq[d + 1], e4.y, s);
            s = fmaf(xq[d + 2], e4.z, s);
            s = fmaf(xq[d + 3], e4.w, s);
        }
        s += __shfl_xor(s, 1, 64);
        s += __shfl_xor(s, 2, 64);       // all 4 lanes now hold the full dot
        float dist = fmaf(s, -2.0f, e2g[c]);
        #pragma unroll
        for (int off = 4; off <= 32; off <<= 1) {
            float od = __shfl_xor(dist, off, 64);
            int   oc = __shfl_xor(c,    off, 64);
            if (od < dist || (od == dist && oc < c)) { dist = od; c = oc; }
        }
        if (l == 0) {
            idx[row] = c;
            atomicAdd(&hist[c], 1);
        }
    }
}

// gather z_q (exact fp32 emb), transposed out, commitment loss
__global__ __launch_bounds__(256)
void vq_gather(const float* __restrict__ z_e, const float* __restrict__ emb,
               const int* __restrict__ idx, float* __restrict__ out,
               float* __restrict__ lossAcc)
{
    __shared__ float es[64 * 259];
    __shared__ int   codes[64];
    __shared__ float red[4];
    const int tid = threadIdx.x;
    const int bb  = blockIdx.x >> 4;
    const int t0  = (blockIdx.x & 15) << 6;
    if (tid < 64) codes[tid] = idx[bb * T_ + t0 + tid];
    __syncthreads();
    for (int p = 0; p < 64; p++) {
        es[p * 259 + tid] = emb[codes[p] * D_ + tid];
    }
    __syncthreads();
    const int t  = tid & 63;
    const int ds = tid >> 6;
    float ls = 0.f;
    #pragma unroll 4
    for (int jj = 0; jj < 64; jj++) {
        int d = ds * 64 + jj;
        float e = es[t * 259 + d];
        int gi = (bb * D_ + d) * T_ + t0 + t;
        float x = z_e[gi];
        out[gi] = e;
        float df = e - x;
        ls += df * df;
    }
    #pragma unroll
    for (int off = 32; off >= 1; off >>= 1) ls += __shfl_down(ls, off, 64);
    if ((tid & 63) == 0) red[tid >> 6] = ls;
    __syncthreads();
    if (tid == 0) atomicAdd(lossAcc, red[0] + red[1] + red[2] + red[3]);
}

__global__ void vq_finalize(const int* __restrict__ hist, const float* __restrict__ lossAcc,
                            float* __restrict__ out_scalars)
{
    __shared__ float red[256];
    const int tid = threadIdx.x;
    float s = 0.f;
    for (int k = tid; k < K_; k += 256) {
        float p = (float)hist[k] * (1.0f / (float)N_);
        s += p * logf(p + 1e-10f);
    }
    red[tid] = s;
    __syncthreads();
    for (int off = 128; off >= 1; off >>= 1) {
        if (tid < off) red[tid] += red[tid + off];
        __syncthreads();
    }
    if (tid == 0) {
        out_scalars[0] = 0.25f * lossAcc[0] * (1.f / (float)(N_ * D_));
        out_scalars[1] = expf(-red[0]);
    }
}

extern "C" void kernel_launch(void* const* d_in, const int* in_sizes, int n_in,
                              void* d_out, int out_size, void* d_ws, size_t ws_size,
                              hipStream_t stream) {
    const float* z_e = (const float*)d_in[0];
    const float* emb = (const float*)d_in[1];
    float* out = (float*)d_out;
    char*  ws  = (char*)d_ws;

    float* e2      = (float*)(ws + WS_E2);
    u16*   cand    = (u16*)(ws + WS_CAND);
    int*   idx     = (int*)(ws + WS_IDX);
    int*   hist    = (int*)(ws + WS_HIST);
    float* lossAcc = (float*)(ws + WS_LOSS);

    // EH (pre-swizzled f16 hi) lives in d_out's first 4MB; vq_gather
    // overwrites the whole region afterwards (stream-ordered, graph-safe).
    f16* EHs = (f16*)d_out;

    vq_prep    <<<1024, 256, 0, stream>>>(emb, EHs, e2, hist);   // + hist/loss zero
    vq_mfma    <<<1024, 256, 0, stream>>>(z_e, EHs, e2, cand);
    vq_refine  <<<512,  256, 0, stream>>>(z_e, emb, e2, cand, idx, hist);
    vq_gather  <<<256,  256, 0, stream>>>(z_e, emb, idx, out, lossAcc);
    vq_finalize<<<1,    256, 0, stream>>>(hist, lossAcc, out + 4194304);
}